// Round 7
// baseline (435.061 us; speedup 1.0000x reference)
//
#include <hip/hip_runtime.h>
#include <hip/hip_bf16.h>
#include <math.h>

typedef __hip_bfloat16 bf16;
typedef __attribute__((ext_vector_type(8))) short short8v;
typedef __attribute__((ext_vector_type(4))) float float4v;

__device__ __forceinline__ float b2f(bf16 v) { return __bfloat162float(v); }
__device__ __forceinline__ float bs2f(unsigned short s) {
    unsigned u = ((unsigned)s) << 16;
    float f; __builtin_memcpy(&f, &u, 4); return f;
}
__device__ __forceinline__ short f2bs(float v) {
    bf16 b = __float2bfloat16(v);
    short s; __builtin_memcpy(&s, &b, 2); return s;
}
__device__ __forceinline__ float lrelu(float v) { return v > 0.f ? v : 0.2f * v; }
__device__ __forceinline__ float ldf(const void* p, size_t i, int bf) {
    return bf ? b2f(((const bf16*)p)[i]) : ((const float*)p)[i];
}
__device__ __forceinline__ int ld_src(const int* ei, int e, int E, int f64, int N) {
    int v = f64 ? (int)(((const long long*)ei)[e]) : ei[e];
    if ((unsigned)v >= (unsigned)N) v = 0;
    return v;
}
__device__ __forceinline__ int ld_dst(const int* ei, int e, int E, int f64, int N) {
    int v = f64 ? (int)(((const long long*)ei)[(size_t)E + e]) : ei[(size_t)E + e];
    if ((unsigned)v >= (unsigned)N) v = 0;
    return v;
}

#define EPB 4096   // edges per block in binning passes
#define SB  9      // bucket shift: 512 nodes per bucket

// ---------------------------------------------------------------------------
// K0: dtype detection. flags[0]=int64 edge index, flags[1]=bf16 floats.
// ---------------------------------------------------------------------------
__global__ void k_detect(const int* __restrict__ ei, const unsigned* __restrict__ xw,
                         int* __restrict__ flags)
{
    __shared__ int s_or[256];
    __shared__ int s_cnt[256];
    int t = threadIdx.x;
    int any = 0, cnt = 0;
    for (int i = t; i < 4096; i += 256) {
        any |= ei[2 * i + 1];
        unsigned e = (xw[i] >> 7) & 0xFFu;
        cnt += (e >= 100u && e <= 134u) ? 1 : 0;
    }
    s_or[t] = any; s_cnt[t] = cnt;
    __syncthreads();
    for (int s = 128; s > 0; s >>= 1) {
        if (t < s) { s_or[t] |= s_or[t + s]; s_cnt[t] += s_cnt[t + s]; }
        __syncthreads();
    }
    if (t == 0) {
        flags[0] = (s_or[0] == 0) ? 1 : 0;
        flags[1] = (s_cnt[0] > 2048) ? 1 : 0;
    }
}

__global__ void k_zero(int* __restrict__ p, int n)
{
    int i = blockIdx.x * blockDim.x + threadIdx.x;
    if (i < n) p[i] = 0;
}

// ---------------------------------------------------------------------------
// CSR build, bucket-local (no global random atomics).
// ---------------------------------------------------------------------------
__global__ void __launch_bounds__(256)
k_bbin_count(const int* __restrict__ ei, const int* __restrict__ flags,
             int* __restrict__ bcnt, int E, int N, int nbuck)
{
    __shared__ int hist[512];
    int t = threadIdx.x;
    for (int j = t; j < nbuck; j += 256) hist[j] = 0;
    __syncthreads();
    int f = flags[0];
    int beg = blockIdx.x * EPB, end = min(E, beg + EPB);
    for (int i = beg + t; i < end; i += 256)
        atomicAdd(&hist[ld_dst(ei, i, E, f, N) >> SB], 1);
    __syncthreads();
    for (int j = t; j < nbuck; j += 256)
        if (hist[j]) atomicAdd(&bcnt[j], hist[j]);
}

__global__ void k_bscan(const int* __restrict__ bcnt, int* __restrict__ bofs,
                        int* __restrict__ bcur, int* __restrict__ offsets,
                        int nbuck, int E, int N)
{
    __shared__ int sh[256];
    int t = threadIdx.x;
    int v = (t < nbuck) ? bcnt[t] : 0;
    sh[t] = v;
    __syncthreads();
    for (int s = 1; s < 256; s <<= 1) {
        int add = (t >= s) ? sh[t - s] : 0;
        __syncthreads();
        sh[t] += add;
        __syncthreads();
    }
    if (t < nbuck) { bofs[t] = sh[t] - v; bcur[t] = sh[t] - v; }
    if (t == 0) { bofs[nbuck] = E; offsets[N] = E; }
}

__global__ void __launch_bounds__(256)
k_bbin_scatter(const int* __restrict__ ei, const int* __restrict__ flags,
               int* __restrict__ bcur, uint2* __restrict__ ebuf,
               int E, int N, int nbuck)
{
    __shared__ int hist[512];
    __shared__ int base[512];
    int t = threadIdx.x;
    for (int j = t; j < nbuck; j += 256) hist[j] = 0;
    __syncthreads();
    int f = flags[0];
    int beg = blockIdx.x * EPB, end = min(E, beg + EPB);
    for (int i = beg + t; i < end; i += 256)
        atomicAdd(&hist[ld_dst(ei, i, E, f, N) >> SB], 1);
    __syncthreads();
    for (int j = t; j < nbuck; j += 256) {
        base[j] = hist[j] ? atomicAdd(&bcur[j], hist[j]) : 0;
        hist[j] = 0;
    }
    __syncthreads();
    for (int i = beg + t; i < end; i += 256) {
        int d = ld_dst(ei, i, E, f, N);
        int s = ld_src(ei, i, E, f, N);
        int b = d >> SB;
        int idx = base[b] + atomicAdd(&hist[b], 1);
        ebuf[idx] = make_uint2((unsigned)s, (unsigned)d);
    }
}

__global__ void __launch_bounds__(256)
k_bucket_csr(const uint2* __restrict__ ebuf, const int* __restrict__ bofs,
             int* __restrict__ offsets, int* __restrict__ adj, int N)
{
    const int npb = 1 << SB;
    __shared__ int hist[npb];
    __shared__ int psum[256];
    int b = blockIdx.x, t = threadIdx.x;
    int n0 = b << SB;
    int ebeg = bofs[b], eend = bofs[b + 1];

    hist[t] = 0; hist[t + 256] = 0;
    __syncthreads();
    for (int i = ebeg + t; i < eend; i += 256)
        atomicAdd(&hist[ebuf[i].y - n0], 1);
    __syncthreads();
    int c0 = hist[2 * t], c1 = hist[2 * t + 1];
    int s = c0 + c1;
    psum[t] = s;
    __syncthreads();
    for (int st = 1; st < 256; st <<= 1) {
        int add = (t >= st) ? psum[t - st] : 0;
        __syncthreads();
        psum[t] += add;
        __syncthreads();
    }
    int run = ebeg + psum[t] - s;
    int node0 = n0 + 2 * t;
    hist[2 * t] = run;
    if (node0 < N) offsets[node0] = run;
    run += c0;
    hist[2 * t + 1] = run;
    if (node0 + 1 < N) offsets[node0 + 1] = run;
    __syncthreads();
    for (int i = ebeg + t; i < eend; i += 256) {
        uint2 e = ebuf[i];
        int pos = atomicAdd(&hist[e.y - n0], 1);
        adj[pos] = (int)e.x;
    }
}

// ---------------------------------------------------------------------------
// K1: h1 = x @ W1 via MFMA 16x16x32 bf16.
// ---------------------------------------------------------------------------
#define GP 136

__global__ void __launch_bounds__(256)
k_gemm1_mfma(const void* __restrict__ x, const void* __restrict__ W1,
             const int* __restrict__ flags, bf16* __restrict__ h1b, int N)
{
    __shared__ short w1t[128 * GP];
    __shared__ short xs[64 * GP];
    int bf = flags[1];
    int t = threadIdx.x;
    int m0 = blockIdx.x * 64;

    for (int idx = t; idx < 16384; idx += 256) {
        int k = idx >> 7, nn = idx & 127;
        w1t[nn * GP + k] = bf ? ((const short*)W1)[idx] : f2bs(((const float*)W1)[idx]);
    }
    for (int idx = t; idx < 8192; idx += 256) {
        int m = idx >> 7, k = idx & 127;
        int gm = m0 + m;
        float v = (gm < N) ? ldf(x, (size_t)gm * 128 + k, bf) : 0.f;
        xs[m * GP + k] = f2bs(v);
    }
    __syncthreads();

    int wv = t >> 6, l = t & 63, lq = l >> 4, lr = l & 15;

    short8v afr[4];
#pragma unroll
    for (int kk = 0; kk < 4; ++kk)
        afr[kk] = *(const short8v*)&xs[(wv * 16 + lr) * GP + kk * 32 + lq * 8];

    float4v acc[8];
#pragma unroll
    for (int ct = 0; ct < 8; ++ct) acc[ct] = (float4v){0.f, 0.f, 0.f, 0.f};

#pragma unroll
    for (int kk = 0; kk < 4; ++kk) {
        short8v a = afr[kk];
#pragma unroll
        for (int ct = 0; ct < 8; ++ct) {
            short8v bfr = *(const short8v*)&w1t[(ct * 16 + lr) * GP + kk * 32 + lq * 8];
            acc[ct] = __builtin_amdgcn_mfma_f32_16x16x32_bf16(a, bfr, acc[ct], 0, 0, 0);
        }
    }

#pragma unroll
    for (int ct = 0; ct < 8; ++ct) {
#pragma unroll
        for (int r = 0; r < 4; ++r) {
            int row = m0 + wv * 16 + lq * 4 + r;
            if (row < N)
                h1b[(size_t)row * 128 + ct * 16 + lr] = __float2bfloat16(acc[ct][r]);
        }
    }
}

// ---------------------------------------------------------------------------
// K2: a_s/a_d from h1b. One wave per node.
// ---------------------------------------------------------------------------
__global__ void k_asd(const bf16* __restrict__ h1b, const void* __restrict__ att_src,
                      const void* __restrict__ att_dst, const int* __restrict__ flags,
                      float* __restrict__ a_s, float* __restrict__ a_d, int N)
{
    int bf = flags[1];
    int gid = blockIdx.x * blockDim.x + threadIdx.x;
    int n = gid >> 6, l = gid & 63;
    if (n >= N) return;
    ushort2 u = *(const ushort2*)((const unsigned short*)h1b + (size_t)n * 128 + 2 * l);
    float v0 = bs2f(u.x), v1 = bs2f(u.y);
    float ps = v0 * ldf(att_src, 2 * l, bf) + v1 * ldf(att_src, 2 * l + 1, bf);
    float pd = v0 * ldf(att_dst, 2 * l, bf) + v1 * ldf(att_dst, 2 * l + 1, bf);
    for (int m = 1; m < 16; m <<= 1) {
        ps += __shfl_xor(ps, m, 64);
        pd += __shfl_xor(pd, m, 64);
    }
    if ((l & 15) == 0) {
        a_s[(size_t)n * 4 + (l >> 4)] = ps;
        a_d[(size_t)n * 4 + (l >> 4)] = pd;
    }
}

// ---------------------------------------------------------------------------
// K7: per-head layer-1 softmax-aggregate. Head-major grid segments.
// 8-lane group per (node, head): lane owns 4 cols (ushort4 = one 64B line
// per edge per group). No LDS, no barriers; denominator replicated across
// lanes; only the fused W2-dot reduces (3-stage shfl). Writes partial
// hpart[n*4+h] = dot(relu(o_slice + b1_slice), W2_slice).
// ---------------------------------------------------------------------------
__global__ void __launch_bounds__(256)
k_hagg(const bf16* __restrict__ h1b, const float* __restrict__ a_s,
       const float* __restrict__ a_d, const int* __restrict__ offsets,
       const int* __restrict__ adj, const void* __restrict__ b1,
       const void* __restrict__ W2, const int* __restrict__ flags,
       float* __restrict__ hpart, int N, int seg)
{
    int bf = flags[1];
    int h = blockIdx.x / seg;
    int nbase = (blockIdx.x % seg) * 32;
    int t = threadIdx.x;
    int g = t >> 3, l = t & 7;
    int n = nbase + g;
    if (n >= N) return;

    int beg = offsets[n], deg = offsets[n + 1] - beg;
    float adh = a_d[(size_t)n * 4 + h];
    const unsigned short* h1u = (const unsigned short*)h1b;
    int coff = h * 32 + l * 4;  // this lane's 4 columns

    // self loop
    float wself = __expf(lrelu(a_s[(size_t)n * 4 + h] + adh));
    ushort4 u = *(const ushort4*)(h1u + ((size_t)n << 7) + coff);
    float a0 = wself * bs2f(u.x), a1 = wself * bs2f(u.y);
    float a2 = wself * bs2f(u.z), a3 = wself * bs2f(u.w);
    float den = wself;

    for (int i = 0; i < deg; ++i) {
        int s = adj[beg + i];                       // lane-uniform broadcast
        float w = __expf(lrelu(a_s[(size_t)s * 4 + h] + adh));
        den += w;
        ushort4 v = *(const ushort4*)(h1u + ((size_t)s << 7) + coff);
        a0 += w * bs2f(v.x);
        a1 += w * bs2f(v.y);
        a2 += w * bs2f(v.z);
        a3 += w * bs2f(v.w);
    }

    float inv = 1.f / (den + 1e-16f);
    float o0 = fmaxf(a0 * inv + ldf(b1, coff + 0, bf), 0.f);
    float o1 = fmaxf(a1 * inv + ldf(b1, coff + 1, bf), 0.f);
    float o2 = fmaxf(a2 * inv + ldf(b1, coff + 2, bf), 0.f);
    float o3 = fmaxf(a3 * inv + ldf(b1, coff + 3, bf), 0.f);

    float p = o0 * ldf(W2, coff + 0, bf) + o1 * ldf(W2, coff + 1, bf)
            + o2 * ldf(W2, coff + 2, bf) + o3 * ldf(W2, coff + 3, bf);
    p += __shfl_xor(p, 1, 64);
    p += __shfl_xor(p, 2, 64);
    p += __shfl_xor(p, 4, 64);
    if (l == 0) hpart[(size_t)n * 4 + h] = p;
}

// sum the 4 head partials -> h2[n]
__global__ void k_h2sum(const float* __restrict__ hpart, float* __restrict__ h2, int N)
{
    int n = blockIdx.x * blockDim.x + threadIdx.x;
    if (n < N) {
        float4 v = *(const float4*)(hpart + (size_t)n * 4);
        h2[n] = v.x + v.y + v.z + v.w;
    }
}

// ---------------------------------------------------------------------------
// K8: layer-2 scalar softmax-aggregate, single pass. 16 lanes per node.
// ---------------------------------------------------------------------------
__global__ void k_agg2(const float* __restrict__ h2, const int* __restrict__ offsets,
                       const int* __restrict__ adj, const void* __restrict__ att_src2,
                       const void* __restrict__ att_dst2, const void* __restrict__ bias2,
                       const int* __restrict__ flags, void* __restrict__ out, int N)
{
    int bf = flags[1];
    int g = (blockIdx.x * blockDim.x + threadIdx.x) >> 4;
    int lane = threadIdx.x & 15;
    if (g >= N) return;
    int n = g;
    float as2 = ldf(att_src2, 0, bf), ad2 = ldf(att_dst2, 0, bf);
    int beg = offsets[n], end = offsets[n + 1], deg = end - beg;
    float hn = h2[n];
    float dterm = hn * ad2;

    float acc = 0.f, den = 0.f;
    if (lane == 0) {
        float ex = __expf(lrelu(hn * as2 + dterm));
        acc = ex * hn; den = ex;
    }
    for (int i = lane; i < deg; i += 16) {
        int s = adj[beg + i];
        float hs = h2[s];
        float ex = __expf(lrelu(hs * as2 + dterm));
        acc += ex * hs; den += ex;
    }
    for (int m = 1; m < 16; m <<= 1) {
        acc += __shfl_xor(acc, m, 64);
        den += __shfl_xor(den, m, 64);
    }
    if (lane == 0) {
        float r = acc / (den + 1e-16f) + ldf(bias2, 0, bf);
        if (bf) ((bf16*)out)[n] = __float2bfloat16(r);
        else    ((float*)out)[n] = r;
    }
}

// ---------------------------------------------------------------------------
extern "C" void kernel_launch(void* const* d_in, const int* in_sizes, int n_in,
                              void* d_out, int out_size, void* d_ws, size_t ws_size,
                              hipStream_t stream)
{
    const void* x        = d_in[0];
    const int*  ei       = (const int*)d_in[1];
    const void* W1       = d_in[2];
    const void* att_src1 = d_in[3];
    const void* att_dst1 = d_in[4];
    const void* b1       = d_in[5];
    const void* W2       = d_in[6];
    const void* att_src2 = d_in[7];
    const void* att_dst2 = d_in[8];
    const void* bias2    = d_in[9];

    int N = in_sizes[0] / 128;
    int E = in_sizes[1] / 2;
    int nbuck = ((N - 1) >> SB) + 1;

    char* ws = (char*)d_ws;
    size_t off = 0;
    auto alloc = [&](size_t bytes) -> void* {
        void* p = ws + off;
        off = (off + bytes + 255) & ~(size_t)255;
        return p;
    };
    int*   flags   = (int*)alloc(256);
    float* a_s     = (float*)alloc((size_t)N * 4 * sizeof(float));
    float* a_d     = (float*)alloc((size_t)N * 4 * sizeof(float));
    float* h2      = (float*)alloc((size_t)N * sizeof(float));
    float* hpart   = (float*)alloc((size_t)N * 4 * sizeof(float));
    int*   offsets = (int*)alloc((size_t)(N + 1) * sizeof(int));
    int*   adj     = (int*)alloc((size_t)E * sizeof(int));
    uint2* ebuf    = (uint2*)alloc((size_t)E * sizeof(uint2));
    int*   bcnt    = (int*)alloc(512 * sizeof(int));
    int*   bofs    = (int*)alloc(516 * sizeof(int));
    int*   bcur    = (int*)alloc(512 * sizeof(int));
    bf16*  h1b     = (bf16*)alloc((size_t)N * 128 * sizeof(bf16));

    k_detect<<<1, 256, 0, stream>>>(ei, (const unsigned*)x, flags);
    k_zero<<<(nbuck + 255) / 256, 256, 0, stream>>>(bcnt, nbuck);

    int ebl = (E + EPB - 1) / EPB;
    k_bbin_count<<<ebl, 256, 0, stream>>>(ei, flags, bcnt, E, N, nbuck);
    k_bscan<<<1, 256, 0, stream>>>(bcnt, bofs, bcur, offsets, nbuck, E, N);
    k_bbin_scatter<<<ebl, 256, 0, stream>>>(ei, flags, bcur, ebuf, E, N, nbuck);
    k_bucket_csr<<<nbuck, 256, 0, stream>>>(ebuf, bofs, offsets, adj, N);

    k_gemm1_mfma<<<(N + 63) / 64, 256, 0, stream>>>(x, W1, flags, h1b, N);
    k_asd<<<((size_t)N * 64 + 255) / 256, 256, 0, stream>>>(
        h1b, att_src1, att_dst1, flags, a_s, a_d, N);

    int seg = (N + 31) / 32;
    k_hagg<<<4 * seg, 256, 0, stream>>>(h1b, a_s, a_d, offsets, adj,
                                        b1, W2, flags, hpart, N, seg);
    k_h2sum<<<(N + 255) / 256, 256, 0, stream>>>(hpart, h2, N);

    k_agg2<<<((size_t)N * 16 + 255) / 256, 256, 0, stream>>>(
        h2, offsets, adj, att_src2, att_dst2, bias2, flags, d_out, N);
}

// Round 8
// 392.171 us; speedup vs baseline: 1.1094x; 1.1094x over previous
//
#include <hip/hip_runtime.h>
#include <hip/hip_bf16.h>
#include <math.h>

typedef __hip_bfloat16 bf16;
typedef __attribute__((ext_vector_type(8))) short short8v;
typedef __attribute__((ext_vector_type(4))) float float4v;

__device__ __forceinline__ float b2f(bf16 v) { return __bfloat162float(v); }
__device__ __forceinline__ float bs2f(unsigned short s) {
    unsigned u = ((unsigned)s) << 16;
    float f; __builtin_memcpy(&f, &u, 4); return f;
}
__device__ __forceinline__ short f2bs(float v) {
    bf16 b = __float2bfloat16(v);
    short s; __builtin_memcpy(&s, &b, 2); return s;
}
__device__ __forceinline__ float lrelu(float v) { return v > 0.f ? v : 0.2f * v; }
__device__ __forceinline__ float ldf(const void* p, size_t i, int bf) {
    return bf ? b2f(((const bf16*)p)[i]) : ((const float*)p)[i];
}
__device__ __forceinline__ int ld_src(const int* ei, int e, int E, int f64, int N) {
    int v = f64 ? (int)(((const long long*)ei)[e]) : ei[e];
    if ((unsigned)v >= (unsigned)N) v = 0;
    return v;
}
__device__ __forceinline__ int ld_dst(const int* ei, int e, int E, int f64, int N) {
    int v = f64 ? (int)(((const long long*)ei)[(size_t)E + e]) : ei[(size_t)E + e];
    if ((unsigned)v >= (unsigned)N) v = 0;
    return v;
}

#define EPB 4096   // edges per block in binning passes
#define SB  8      // bucket shift: 256 nodes per bucket (391 buckets @ N=100k)

// ---------------------------------------------------------------------------
// K0: dtype detection. flags[0]=int64 edge index, flags[1]=bf16 floats.
// ---------------------------------------------------------------------------
__global__ void k_detect(const int* __restrict__ ei, const unsigned* __restrict__ xw,
                         int* __restrict__ flags)
{
    __shared__ int s_or[256];
    __shared__ int s_cnt[256];
    int t = threadIdx.x;
    int any = 0, cnt = 0;
    for (int i = t; i < 4096; i += 256) {
        any |= ei[2 * i + 1];
        unsigned e = (xw[i] >> 7) & 0xFFu;
        cnt += (e >= 100u && e <= 134u) ? 1 : 0;
    }
    s_or[t] = any; s_cnt[t] = cnt;
    __syncthreads();
    for (int s = 128; s > 0; s >>= 1) {
        if (t < s) { s_or[t] |= s_or[t + s]; s_cnt[t] += s_cnt[t + s]; }
        __syncthreads();
    }
    if (t == 0) {
        flags[0] = (s_or[0] == 0) ? 1 : 0;
        flags[1] = (s_cnt[0] > 2048) ? 1 : 0;
    }
}

__global__ void k_zero(int* __restrict__ p, int n)
{
    int i = blockIdx.x * blockDim.x + threadIdx.x;
    if (i < n) p[i] = 0;
}

// ---------------------------------------------------------------------------
// CSR build, bucket-local (no global random atomics). nbuck <= 512.
// ---------------------------------------------------------------------------
__global__ void __launch_bounds__(256)
k_bbin_count(const int* __restrict__ ei, const int* __restrict__ flags,
             int* __restrict__ bcnt, int E, int N, int nbuck)
{
    __shared__ int hist[512];
    int t = threadIdx.x;
    for (int j = t; j < nbuck; j += 256) hist[j] = 0;
    __syncthreads();
    int f = flags[0];
    int beg = blockIdx.x * EPB, end = min(E, beg + EPB);
    for (int i = beg + t; i < end; i += 256)
        atomicAdd(&hist[ld_dst(ei, i, E, f, N) >> SB], 1);
    __syncthreads();
    for (int j = t; j < nbuck; j += 256)
        if (hist[j]) atomicAdd(&bcnt[j], hist[j]);
}

__global__ void __launch_bounds__(512)
k_bscan(const int* __restrict__ bcnt, int* __restrict__ bofs,
        int* __restrict__ bcur, int* __restrict__ offsets,
        int nbuck, int E, int N)
{
    __shared__ int sh[512];
    int t = threadIdx.x;
    int v = (t < nbuck) ? bcnt[t] : 0;
    sh[t] = v;
    __syncthreads();
    for (int s = 1; s < 512; s <<= 1) {
        int add = (t >= s) ? sh[t - s] : 0;
        __syncthreads();
        sh[t] += add;
        __syncthreads();
    }
    if (t < nbuck) { bofs[t] = sh[t] - v; bcur[t] = sh[t] - v; }
    if (t == 0) { bofs[nbuck] = E; offsets[N] = E; }
}

__global__ void __launch_bounds__(256)
k_bbin_scatter(const int* __restrict__ ei, const int* __restrict__ flags,
               int* __restrict__ bcur, uint2* __restrict__ ebuf,
               int E, int N, int nbuck)
{
    __shared__ int hist[512];
    __shared__ int base[512];
    int t = threadIdx.x;
    for (int j = t; j < nbuck; j += 256) hist[j] = 0;
    __syncthreads();
    int f = flags[0];
    int beg = blockIdx.x * EPB, end = min(E, beg + EPB);
    for (int i = beg + t; i < end; i += 256)
        atomicAdd(&hist[ld_dst(ei, i, E, f, N) >> SB], 1);
    __syncthreads();
    for (int j = t; j < nbuck; j += 256) {
        base[j] = hist[j] ? atomicAdd(&bcur[j], hist[j]) : 0;
        hist[j] = 0;
    }
    __syncthreads();
    for (int i = beg + t; i < end; i += 256) {
        int d = ld_dst(ei, i, E, f, N);
        int s = ld_src(ei, i, E, f, N);
        int b = d >> SB;
        int idx = base[b] + atomicAdd(&hist[b], 1);
        ebuf[idx] = make_uint2((unsigned)s, (unsigned)d);
    }
}

__global__ void __launch_bounds__(256)
k_bucket_csr(const uint2* __restrict__ ebuf, const int* __restrict__ bofs,
             int* __restrict__ offsets, int* __restrict__ adj, int N)
{
    const int npb = 1 << SB;          // 256 nodes per bucket
    __shared__ int hist[npb];
    __shared__ int psum[256];
    int b = blockIdx.x, t = threadIdx.x;
    int n0 = b << SB;
    int ebeg = bofs[b], eend = bofs[b + 1];

    hist[t] = 0;
    __syncthreads();
    for (int i = ebeg + t; i < eend; i += 256)
        atomicAdd(&hist[ebuf[i].y - n0], 1);
    __syncthreads();
    int c = hist[t];
    psum[t] = c;
    __syncthreads();
    for (int st = 1; st < 256; st <<= 1) {
        int add = (t >= st) ? psum[t - st] : 0;
        __syncthreads();
        psum[t] += add;
        __syncthreads();
    }
    int run = ebeg + psum[t] - c;   // exclusive
    int node = n0 + t;
    hist[t] = run;
    if (node < N) offsets[node] = run;
    __syncthreads();
    for (int i = ebeg + t; i < eend; i += 256) {
        uint2 e = ebuf[i];
        int pos = atomicAdd(&hist[e.y - n0], 1);
        adj[pos] = (int)e.x;
    }
}

// ---------------------------------------------------------------------------
// K1: h1 = x @ W1 via MFMA 16x16x32 bf16.
// ---------------------------------------------------------------------------
#define GP 136

__global__ void __launch_bounds__(256)
k_gemm1_mfma(const void* __restrict__ x, const void* __restrict__ W1,
             const int* __restrict__ flags, bf16* __restrict__ h1b, int N)
{
    __shared__ short w1t[128 * GP];
    __shared__ short xs[64 * GP];
    int bf = flags[1];
    int t = threadIdx.x;
    int m0 = blockIdx.x * 64;

    for (int idx = t; idx < 16384; idx += 256) {
        int k = idx >> 7, nn = idx & 127;
        w1t[nn * GP + k] = bf ? ((const short*)W1)[idx] : f2bs(((const float*)W1)[idx]);
    }
    for (int idx = t; idx < 8192; idx += 256) {
        int m = idx >> 7, k = idx & 127;
        int gm = m0 + m;
        float v = (gm < N) ? ldf(x, (size_t)gm * 128 + k, bf) : 0.f;
        xs[m * GP + k] = f2bs(v);
    }
    __syncthreads();

    int wv = t >> 6, l = t & 63, lq = l >> 4, lr = l & 15;

    short8v afr[4];
#pragma unroll
    for (int kk = 0; kk < 4; ++kk)
        afr[kk] = *(const short8v*)&xs[(wv * 16 + lr) * GP + kk * 32 + lq * 8];

    float4v acc[8];
#pragma unroll
    for (int ct = 0; ct < 8; ++ct) acc[ct] = (float4v){0.f, 0.f, 0.f, 0.f};

#pragma unroll
    for (int kk = 0; kk < 4; ++kk) {
        short8v a = afr[kk];
#pragma unroll
        for (int ct = 0; ct < 8; ++ct) {
            short8v bfr = *(const short8v*)&w1t[(ct * 16 + lr) * GP + kk * 32 + lq * 8];
            acc[ct] = __builtin_amdgcn_mfma_f32_16x16x32_bf16(a, bfr, acc[ct], 0, 0, 0);
        }
    }

#pragma unroll
    for (int ct = 0; ct < 8; ++ct) {
#pragma unroll
        for (int r = 0; r < 4; ++r) {
            int row = m0 + wv * 16 + lq * 4 + r;
            if (row < N)
                h1b[(size_t)row * 128 + ct * 16 + lr] = __float2bfloat16(acc[ct][r]);
        }
    }
}

// ---------------------------------------------------------------------------
// K2: a_s/a_d from h1b. One wave per node.
// ---------------------------------------------------------------------------
__global__ void k_asd(const bf16* __restrict__ h1b, const void* __restrict__ att_src,
                      const void* __restrict__ att_dst, const int* __restrict__ flags,
                      float* __restrict__ a_s, float* __restrict__ a_d, int N)
{
    int bf = flags[1];
    int gid = blockIdx.x * blockDim.x + threadIdx.x;
    int n = gid >> 6, l = gid & 63;
    if (n >= N) return;
    ushort2 u = *(const ushort2*)((const unsigned short*)h1b + (size_t)n * 128 + 2 * l);
    float v0 = bs2f(u.x), v1 = bs2f(u.y);
    float ps = v0 * ldf(att_src, 2 * l, bf) + v1 * ldf(att_src, 2 * l + 1, bf);
    float pd = v0 * ldf(att_dst, 2 * l, bf) + v1 * ldf(att_dst, 2 * l + 1, bf);
    for (int m = 1; m < 16; m <<= 1) {
        ps += __shfl_xor(ps, m, 64);
        pd += __shfl_xor(pd, m, 64);
    }
    if ((l & 15) == 0) {
        a_s[(size_t)n * 4 + (l >> 4)] = ps;
        a_d[(size_t)n * 4 + (l >> 4)] = pd;
    }
}

// ---------------------------------------------------------------------------
// K7: layer-1 softmax-aggregate, full-row barrier-free. One 32-lane group
// per node: lane owns head l>>3, cols (l&7)*4 via ushort4 (group covers the
// whole 256B row = 2 cache lines, zero granule waste). Denominator
// replicated per-head across 8 lanes (no reduction). Fused +b1, ReLU, W2
// dot (5-stage shfl) -> h2[n] directly. No LDS, no __syncthreads.
// ---------------------------------------------------------------------------
__global__ void __launch_bounds__(256)
k_hagg32(const bf16* __restrict__ h1b, const float* __restrict__ a_s,
         const float* __restrict__ a_d, const int* __restrict__ offsets,
         const int* __restrict__ adj, const void* __restrict__ b1,
         const void* __restrict__ W2, const int* __restrict__ flags,
         float* __restrict__ h2, int N)
{
    int bf = flags[1];
    int t = threadIdx.x;
    int g = t >> 5, l = t & 31;
    int n = blockIdx.x * 8 + g;
    if (n >= N) return;
    int h = l >> 3;
    int coff = h * 32 + (l & 7) * 4;

    int beg = offsets[n], deg = offsets[n + 1] - beg;
    float adh = a_d[(size_t)n * 4 + h];
    const unsigned short* h1u = (const unsigned short*)h1b;

    // self loop
    float wself = __expf(lrelu(a_s[(size_t)n * 4 + h] + adh));
    ushort4 u = *(const ushort4*)(h1u + ((size_t)n << 7) + coff);
    float a0 = wself * bs2f(u.x), a1 = wself * bs2f(u.y);
    float a2 = wself * bs2f(u.z), a3 = wself * bs2f(u.w);
    float den = wself;

    for (int i = 0; i < deg; ++i) {
        int s = adj[beg + i];                       // group-uniform broadcast
        float w = __expf(lrelu(a_s[(size_t)s * 4 + h] + adh));  // L2-resident
        den += w;
        ushort4 v = *(const ushort4*)(h1u + ((size_t)s << 7) + coff);
        a0 += w * bs2f(v.x);
        a1 += w * bs2f(v.y);
        a2 += w * bs2f(v.z);
        a3 += w * bs2f(v.w);
    }

    float inv = 1.f / (den + 1e-16f);
    float o0 = fmaxf(a0 * inv + ldf(b1, coff + 0, bf), 0.f);
    float o1 = fmaxf(a1 * inv + ldf(b1, coff + 1, bf), 0.f);
    float o2 = fmaxf(a2 * inv + ldf(b1, coff + 2, bf), 0.f);
    float o3 = fmaxf(a3 * inv + ldf(b1, coff + 3, bf), 0.f);

    float p = o0 * ldf(W2, coff + 0, bf) + o1 * ldf(W2, coff + 1, bf)
            + o2 * ldf(W2, coff + 2, bf) + o3 * ldf(W2, coff + 3, bf);
    p += __shfl_xor(p, 1, 64);
    p += __shfl_xor(p, 2, 64);
    p += __shfl_xor(p, 4, 64);
    p += __shfl_xor(p, 8, 64);
    p += __shfl_xor(p, 16, 64);
    if (l == 0) h2[n] = p;
}

// ---------------------------------------------------------------------------
// K8: layer-2 scalar softmax-aggregate, single pass. 16 lanes per node.
// ---------------------------------------------------------------------------
__global__ void k_agg2(const float* __restrict__ h2, const int* __restrict__ offsets,
                       const int* __restrict__ adj, const void* __restrict__ att_src2,
                       const void* __restrict__ att_dst2, const void* __restrict__ bias2,
                       const int* __restrict__ flags, void* __restrict__ out, int N)
{
    int bf = flags[1];
    int g = (blockIdx.x * blockDim.x + threadIdx.x) >> 4;
    int lane = threadIdx.x & 15;
    if (g >= N) return;
    int n = g;
    float as2 = ldf(att_src2, 0, bf), ad2 = ldf(att_dst2, 0, bf);
    int beg = offsets[n], end = offsets[n + 1], deg = end - beg;
    float hn = h2[n];
    float dterm = hn * ad2;

    float acc = 0.f, den = 0.f;
    if (lane == 0) {
        float ex = __expf(lrelu(hn * as2 + dterm));
        acc = ex * hn; den = ex;
    }
    for (int i = lane; i < deg; i += 16) {
        int s = adj[beg + i];
        float hs = h2[s];
        float ex = __expf(lrelu(hs * as2 + dterm));
        acc += ex * hs; den += ex;
    }
    for (int m = 1; m < 16; m <<= 1) {
        acc += __shfl_xor(acc, m, 64);
        den += __shfl_xor(den, m, 64);
    }
    if (lane == 0) {
        float r = acc / (den + 1e-16f) + ldf(bias2, 0, bf);
        if (bf) ((bf16*)out)[n] = __float2bfloat16(r);
        else    ((float*)out)[n] = r;
    }
}

// ---------------------------------------------------------------------------
extern "C" void kernel_launch(void* const* d_in, const int* in_sizes, int n_in,
                              void* d_out, int out_size, void* d_ws, size_t ws_size,
                              hipStream_t stream)
{
    const void* x        = d_in[0];
    const int*  ei       = (const int*)d_in[1];
    const void* W1       = d_in[2];
    const void* att_src1 = d_in[3];
    const void* att_dst1 = d_in[4];
    const void* b1       = d_in[5];
    const void* W2       = d_in[6];
    const void* att_src2 = d_in[7];
    const void* att_dst2 = d_in[8];
    const void* bias2    = d_in[9];

    int N = in_sizes[0] / 128;
    int E = in_sizes[1] / 2;
    int nbuck = ((N - 1) >> SB) + 1;   // 391 @ N=100k (<= 512)

    char* ws = (char*)d_ws;
    size_t off = 0;
    auto alloc = [&](size_t bytes) -> void* {
        void* p = ws + off;
        off = (off + bytes + 255) & ~(size_t)255;
        return p;
    };
    int*   flags   = (int*)alloc(256);
    float* a_s     = (float*)alloc((size_t)N * 4 * sizeof(float));
    float* a_d     = (float*)alloc((size_t)N * 4 * sizeof(float));
    float* h2      = (float*)alloc((size_t)N * sizeof(float));
    int*   offsets = (int*)alloc((size_t)(N + 1) * sizeof(int));
    int*   adj     = (int*)alloc((size_t)E * sizeof(int));
    uint2* ebuf    = (uint2*)alloc((size_t)E * sizeof(uint2));
    int*   bcnt    = (int*)alloc(1024 * sizeof(int));
    int*   bofs    = (int*)alloc(1028 * sizeof(int));
    int*   bcur    = (int*)alloc(1024 * sizeof(int));
    bf16*  h1b     = (bf16*)alloc((size_t)N * 128 * sizeof(bf16));

    k_detect<<<1, 256, 0, stream>>>(ei, (const unsigned*)x, flags);
    k_zero<<<(nbuck + 255) / 256, 256, 0, stream>>>(bcnt, nbuck);

    int ebl = (E + EPB - 1) / EPB;
    k_bbin_count<<<ebl, 256, 0, stream>>>(ei, flags, bcnt, E, N, nbuck);
    k_bscan<<<1, 512, 0, stream>>>(bcnt, bofs, bcur, offsets, nbuck, E, N);
    k_bbin_scatter<<<ebl, 256, 0, stream>>>(ei, flags, bcur, ebuf, E, N, nbuck);
    k_bucket_csr<<<nbuck, 256, 0, stream>>>(ebuf, bofs, offsets, adj, N);

    k_gemm1_mfma<<<(N + 63) / 64, 256, 0, stream>>>(x, W1, flags, h1b, N);
    k_asd<<<((size_t)N * 64 + 255) / 256, 256, 0, stream>>>(
        h1b, att_src1, att_dst1, flags, a_s, a_d, N);

    k_hagg32<<<(N + 7) / 8, 256, 0, stream>>>(h1b, a_s, a_d, offsets, adj,
                                              b1, W2, flags, h2, N);

    k_agg2<<<((size_t)N * 16 + 255) / 256, 256, 0, stream>>>(
        h2, offsets, adj, att_src2, att_dst2, bias2, flags, d_out, N);
}

// Round 9
// 289.567 us; speedup vs baseline: 1.5025x; 1.3543x over previous
//
#include <hip/hip_runtime.h>
#include <hip/hip_bf16.h>
#include <math.h>

typedef __hip_bfloat16 bf16;
typedef __attribute__((ext_vector_type(8))) short short8v;
typedef __attribute__((ext_vector_type(4))) float float4v;

__device__ __forceinline__ float b2f(bf16 v) { return __bfloat162float(v); }
__device__ __forceinline__ float bs2f(unsigned short s) {
    unsigned u = ((unsigned)s) << 16;
    float f; __builtin_memcpy(&f, &u, 4); return f;
}
__device__ __forceinline__ short f2bs(float v) {
    bf16 b = __float2bfloat16(v);
    short s; __builtin_memcpy(&s, &b, 2); return s;
}
__device__ __forceinline__ float lrelu(float v) { return v > 0.f ? v : 0.2f * v; }
__device__ __forceinline__ float ldf(const void* p, size_t i, int bf) {
    return bf ? b2f(((const bf16*)p)[i]) : ((const float*)p)[i];
}
__device__ __forceinline__ int ld_src(const int* ei, int e, int E, int f64, int N) {
    int v = f64 ? (int)(((const long long*)ei)[e]) : ei[e];
    if ((unsigned)v >= (unsigned)N) v = 0;
    return v;
}
__device__ __forceinline__ int ld_dst(const int* ei, int e, int E, int f64, int N) {
    int v = f64 ? (int)(((const long long*)ei)[(size_t)E + e]) : ei[(size_t)E + e];
    if ((unsigned)v >= (unsigned)N) v = 0;
    return v;
}

#define EPB 4096   // edges per block in binning passes
#define SB  8      // bucket shift: 256 nodes per bucket

// ---------------------------------------------------------------------------
// K0: dtype detection. flags[0]=int64 edge index, flags[1]=bf16 floats.
// ---------------------------------------------------------------------------
__global__ void k_detect(const int* __restrict__ ei, const unsigned* __restrict__ xw,
                         int* __restrict__ flags)
{
    __shared__ int s_or[256];
    __shared__ int s_cnt[256];
    int t = threadIdx.x;
    int any = 0, cnt = 0;
    for (int i = t; i < 4096; i += 256) {
        any |= ei[2 * i + 1];
        unsigned e = (xw[i] >> 7) & 0xFFu;
        cnt += (e >= 100u && e <= 134u) ? 1 : 0;
    }
    s_or[t] = any; s_cnt[t] = cnt;
    __syncthreads();
    for (int s = 128; s > 0; s >>= 1) {
        if (t < s) { s_or[t] |= s_or[t + s]; s_cnt[t] += s_cnt[t + s]; }
        __syncthreads();
    }
    if (t == 0) {
        flags[0] = (s_or[0] == 0) ? 1 : 0;
        flags[1] = (s_cnt[0] > 2048) ? 1 : 0;
    }
}

__global__ void k_zero(int* __restrict__ p, int n)
{
    int i = blockIdx.x * blockDim.x + threadIdx.x;
    if (i < n) p[i] = 0;
}

// ---------------------------------------------------------------------------
// W1 -> bf16 in B-fragment order: w1frag[((ct*4+kk)*64 + l)*8 + j]
//   = W1[k = kk*32 + (l>>4)*8 + j][n = ct*16 + (l&15)]   (one-time, 16384 el)
// ---------------------------------------------------------------------------
__global__ void k_w1frag(const void* __restrict__ W1, const int* __restrict__ flags,
                         short* __restrict__ w1frag)
{
    int bf = flags[1];
    int idx = blockIdx.x * 256 + threadIdx.x;
    if (idx >= 16384) return;
    int j = idx & 7, l = (idx >> 3) & 63, kk = (idx >> 9) & 3, ct = idx >> 11;
    int k = kk * 32 + (l >> 4) * 8 + j;
    int n = ct * 16 + (l & 15);
    w1frag[idx] = bf ? ((const short*)W1)[k * 128 + n]
                     : f2bs(((const float*)W1)[k * 128 + n]);
}

// ---------------------------------------------------------------------------
// CSR build, bucket-local (no global random atomics). nbuck <= 512.
// ---------------------------------------------------------------------------
__global__ void __launch_bounds__(256)
k_bbin_count(const int* __restrict__ ei, const int* __restrict__ flags,
             int* __restrict__ bcnt, int E, int N, int nbuck)
{
    __shared__ int hist[512];
    int t = threadIdx.x;
    for (int j = t; j < nbuck; j += 256) hist[j] = 0;
    __syncthreads();
    int f = flags[0];
    int beg = blockIdx.x * EPB, end = min(E, beg + EPB);
    for (int i = beg + t; i < end; i += 256)
        atomicAdd(&hist[ld_dst(ei, i, E, f, N) >> SB], 1);
    __syncthreads();
    for (int j = t; j < nbuck; j += 256)
        if (hist[j]) atomicAdd(&bcnt[j], hist[j]);
}

__global__ void __launch_bounds__(512)
k_bscan(const int* __restrict__ bcnt, int* __restrict__ bofs,
        int* __restrict__ bcur, int* __restrict__ offsets,
        int nbuck, int E, int N)
{
    __shared__ int sh[512];
    int t = threadIdx.x;
    int v = (t < nbuck) ? bcnt[t] : 0;
    sh[t] = v;
    __syncthreads();
    for (int s = 1; s < 512; s <<= 1) {
        int add = (t >= s) ? sh[t - s] : 0;
        __syncthreads();
        sh[t] += add;
        __syncthreads();
    }
    if (t < nbuck) { bofs[t] = sh[t] - v; bcur[t] = sh[t] - v; }
    if (t == 0) { bofs[nbuck] = E; offsets[N] = E; }
}

__global__ void __launch_bounds__(256)
k_bbin_scatter(const int* __restrict__ ei, const int* __restrict__ flags,
               int* __restrict__ bcur, uint2* __restrict__ ebuf,
               int E, int N, int nbuck)
{
    __shared__ int hist[512];
    __shared__ int base[512];
    int t = threadIdx.x;
    for (int j = t; j < nbuck; j += 256) hist[j] = 0;
    __syncthreads();
    int f = flags[0];
    int beg = blockIdx.x * EPB, end = min(E, beg + EPB);
    for (int i = beg + t; i < end; i += 256)
        atomicAdd(&hist[ld_dst(ei, i, E, f, N) >> SB], 1);
    __syncthreads();
    for (int j = t; j < nbuck; j += 256) {
        base[j] = hist[j] ? atomicAdd(&bcur[j], hist[j]) : 0;
        hist[j] = 0;
    }
    __syncthreads();
    for (int i = beg + t; i < end; i += 256) {
        int d = ld_dst(ei, i, E, f, N);
        int s = ld_src(ei, i, E, f, N);
        int b = d >> SB;
        int idx = base[b] + atomicAdd(&hist[b], 1);
        ebuf[idx] = make_uint2((unsigned)s, (unsigned)d);
    }
}

__global__ void __launch_bounds__(256)
k_bucket_csr(const uint2* __restrict__ ebuf, const int* __restrict__ bofs,
             int* __restrict__ offsets, int* __restrict__ adj, int N)
{
    const int npb = 1 << SB;
    __shared__ int hist[npb];
    __shared__ int psum[256];
    int b = blockIdx.x, t = threadIdx.x;
    int n0 = b << SB;
    int ebeg = bofs[b], eend = bofs[b + 1];

    hist[t] = 0;
    __syncthreads();
    for (int i = ebeg + t; i < eend; i += 256)
        atomicAdd(&hist[ebuf[i].y - n0], 1);
    __syncthreads();
    int c = hist[t];
    psum[t] = c;
    __syncthreads();
    for (int st = 1; st < 256; st <<= 1) {
        int add = (t >= st) ? psum[t - st] : 0;
        __syncthreads();
        psum[t] += add;
        __syncthreads();
    }
    int run = ebeg + psum[t] - c;
    int node = n0 + t;
    hist[t] = run;
    if (node < N) offsets[node] = run;
    __syncthreads();
    for (int i = ebeg + t; i < eend; i += 256) {
        uint2 e = ebuf[i];
        int pos = atomicAdd(&hist[e.y - n0], 1);
        adj[pos] = (int)e.x;
    }
}

// ---------------------------------------------------------------------------
// K1: h1 = x @ W1 via MFMA, LDS-free operands. A-frags direct from x,
// B-frags from w1frag (coalesced 16B, L2-resident). LDS only for the C
// transpose (pad 132 shorts -> all accesses <=2-way). Fused a_s/a_d.
// Block = 256 thr (4 waves), 64 rows; wave owns 16 rows x 128 cols.
// ---------------------------------------------------------------------------
#define GPS 132

__global__ void __launch_bounds__(256)
k_gemm2(const void* __restrict__ x, const short* __restrict__ w1frag,
        const void* __restrict__ att_src, const void* __restrict__ att_dst,
        const int* __restrict__ flags, bf16* __restrict__ h1b,
        float* __restrict__ a_s, float* __restrict__ a_d, int N)
{
    __shared__ short sm[4][16 * GPS];   // 16,896 B
    int bf = flags[1];
    int t = threadIdx.x, wv = t >> 6, l = t & 63, lq = l >> 4, lr = l & 15;
    int m0 = blockIdx.x * 64 + wv * 16;

    // ---- A-frags straight from x ----
    int arow = m0 + lr;
    if (arow >= N) arow = N - 1;
    short8v afr[4];
    if (bf) {
        const unsigned short* xp = (const unsigned short*)x + (size_t)arow * 128;
#pragma unroll
        for (int kk = 0; kk < 4; ++kk)
            afr[kk] = *(const short8v*)(xp + kk * 32 + lq * 8);
    } else {
        const float* xp = (const float*)x + (size_t)arow * 128;
#pragma unroll
        for (int kk = 0; kk < 4; ++kk) {
            float4 f0 = *(const float4*)(xp + kk * 32 + lq * 8);
            float4 f1 = *(const float4*)(xp + kk * 32 + lq * 8 + 4);
            short8v a;
            a[0] = f2bs(f0.x); a[1] = f2bs(f0.y); a[2] = f2bs(f0.z); a[3] = f2bs(f0.w);
            a[4] = f2bs(f1.x); a[5] = f2bs(f1.y); a[6] = f2bs(f1.z); a[7] = f2bs(f1.w);
            afr[kk] = a;
        }
    }

    float4v acc[8];
#pragma unroll
    for (int ct = 0; ct < 8; ++ct) acc[ct] = (float4v){0.f, 0.f, 0.f, 0.f};

#pragma unroll
    for (int kk = 0; kk < 4; ++kk) {
        short8v a = afr[kk];
#pragma unroll
        for (int ct = 0; ct < 8; ++ct) {
            short8v b = *(const short8v*)(w1frag + (((ct * 4 + kk) * 64 + l) << 3));
            acc[ct] = __builtin_amdgcn_mfma_f32_16x16x32_bf16(a, b, acc[ct], 0, 0, 0);
        }
    }

    // ---- C transpose through LDS (writes: quads on disjoint bank groups) ----
#pragma unroll
    for (int ct = 0; ct < 8; ++ct)
#pragma unroll
        for (int r = 0; r < 4; ++r)
            sm[wv][(lq * 4 + r) * GPS + ct * 16 + lr] = f2bs(acc[ct][r]);
    __syncthreads();

    // ---- coalesced store + fused att dots ----
    int c0 = (l & 7) * 16;          // this lane's 16-col chunk (within one head)
    float asv[16], adv[16];
#pragma unroll
    for (int c = 0; c < 16; ++c) {
        asv[c] = ldf(att_src, c0 + c, bf);
        adv[c] = ldf(att_dst, c0 + c, bf);
    }
#pragma unroll
    for (int p = 0; p < 2; ++p) {
        int rrow = p * 8 + (l >> 3);
        int gn = m0 + rrow;
        const short* srcp = &sm[wv][rrow * GPS + c0];
        short8v v0 = *(const short8v*)srcp;
        short8v v1 = *(const short8v*)(srcp + 8);
        if (gn < N) {
            unsigned short* dst = (unsigned short*)h1b + (size_t)gn * 128 + c0;
            *(short8v*)dst = v0;
            *(short8v*)(dst + 8) = v1;
        }
        float ds = 0.f, dd = 0.f;
#pragma unroll
        for (int c = 0; c < 8; ++c) {
            float fv = bs2f((unsigned short)v0[c]);
            ds += fv * asv[c]; dd += fv * adv[c];
        }
#pragma unroll
        for (int c = 0; c < 8; ++c) {
            float fv = bs2f((unsigned short)v1[c]);
            ds += fv * asv[8 + c]; dd += fv * adv[8 + c];
        }
        ds += __shfl_xor(ds, 1, 64);
        dd += __shfl_xor(dd, 1, 64);
        if (gn < N && ((l & 1) == 0)) {
            int h = (l & 7) >> 1;
            a_s[(size_t)gn * 4 + h] = ds;
            a_d[(size_t)gn * 4 + h] = dd;
        }
    }
}

// ---------------------------------------------------------------------------
// K7: layer-1 softmax-aggregate, full-row barrier-free, unroll-2.
// One 32-lane group per node; lane owns head l>>3, 4 cols via ushort4.
// ---------------------------------------------------------------------------
__global__ void __launch_bounds__(256)
k_hagg32(const bf16* __restrict__ h1b, const float* __restrict__ a_s,
         const float* __restrict__ a_d, const int* __restrict__ offsets,
         const int* __restrict__ adj, const void* __restrict__ b1,
         const void* __restrict__ W2, const int* __restrict__ flags,
         float* __restrict__ h2, int N)
{
    int bf = flags[1];
    int t = threadIdx.x;
    int g = t >> 5, l = t & 31;
    int n = blockIdx.x * 8 + g;
    if (n >= N) return;
    int h = l >> 3;
    int coff = h * 32 + (l & 7) * 4;

    int beg = offsets[n], deg = offsets[n + 1] - beg;
    float adh = a_d[(size_t)n * 4 + h];
    const unsigned short* h1u = (const unsigned short*)h1b;

    float wself = __expf(lrelu(a_s[(size_t)n * 4 + h] + adh));
    ushort4 u = *(const ushort4*)(h1u + ((size_t)n << 7) + coff);
    float a0 = wself * bs2f(u.x), a1 = wself * bs2f(u.y);
    float a2 = wself * bs2f(u.z), a3 = wself * bs2f(u.w);
    float den = wself;

    int i = 0;
    for (; i + 2 <= deg; i += 2) {
        int s0 = adj[beg + i];
        int s1 = adj[beg + i + 1];
        float w0 = __expf(lrelu(a_s[(size_t)s0 * 4 + h] + adh));
        float w1 = __expf(lrelu(a_s[(size_t)s1 * 4 + h] + adh));
        ushort4 v0 = *(const ushort4*)(h1u + ((size_t)s0 << 7) + coff);
        ushort4 v1 = *(const ushort4*)(h1u + ((size_t)s1 << 7) + coff);
        den += w0 + w1;
        a0 += w0 * bs2f(v0.x) + w1 * bs2f(v1.x);
        a1 += w0 * bs2f(v0.y) + w1 * bs2f(v1.y);
        a2 += w0 * bs2f(v0.z) + w1 * bs2f(v1.z);
        a3 += w0 * bs2f(v0.w) + w1 * bs2f(v1.w);
    }
    if (i < deg) {
        int s0 = adj[beg + i];
        float w0 = __expf(lrelu(a_s[(size_t)s0 * 4 + h] + adh));
        ushort4 v0 = *(const ushort4*)(h1u + ((size_t)s0 << 7) + coff);
        den += w0;
        a0 += w0 * bs2f(v0.x);
        a1 += w0 * bs2f(v0.y);
        a2 += w0 * bs2f(v0.z);
        a3 += w0 * bs2f(v0.w);
    }

    float inv = 1.f / (den + 1e-16f);
    float o0 = fmaxf(a0 * inv + ldf(b1, coff + 0, bf), 0.f);
    float o1 = fmaxf(a1 * inv + ldf(b1, coff + 1, bf), 0.f);
    float o2 = fmaxf(a2 * inv + ldf(b1, coff + 2, bf), 0.f);
    float o3 = fmaxf(a3 * inv + ldf(b1, coff + 3, bf), 0.f);

    float p = o0 * ldf(W2, coff + 0, bf) + o1 * ldf(W2, coff + 1, bf)
            + o2 * ldf(W2, coff + 2, bf) + o3 * ldf(W2, coff + 3, bf);
    p += __shfl_xor(p, 1, 64);
    p += __shfl_xor(p, 2, 64);
    p += __shfl_xor(p, 4, 64);
    p += __shfl_xor(p, 8, 64);
    p += __shfl_xor(p, 16, 64);
    if (l == 0) h2[n] = p;
}

// ---------------------------------------------------------------------------
// K8: layer-2 scalar softmax-aggregate, single pass. 16 lanes per node.
// ---------------------------------------------------------------------------
__global__ void k_agg2(const float* __restrict__ h2, const int* __restrict__ offsets,
                       const int* __restrict__ adj, const void* __restrict__ att_src2,
                       const void* __restrict__ att_dst2, const void* __restrict__ bias2,
                       const int* __restrict__ flags, void* __restrict__ out, int N)
{
    int bf = flags[1];
    int g = (blockIdx.x * blockDim.x + threadIdx.x) >> 4;
    int lane = threadIdx.x & 15;
    if (g >= N) return;
    int n = g;
    float as2 = ldf(att_src2, 0, bf), ad2 = ldf(att_dst2, 0, bf);
    int beg = offsets[n], end = offsets[n + 1], deg = end - beg;
    float hn = h2[n];
    float dterm = hn * ad2;

    float acc = 0.f, den = 0.f;
    if (lane == 0) {
        float ex = __expf(lrelu(hn * as2 + dterm));
        acc = ex * hn; den = ex;
    }
    for (int i = lane; i < deg; i += 16) {
        int s = adj[beg + i];
        float hs = h2[s];
        float ex = __expf(lrelu(hs * as2 + dterm));
        acc += ex * hs; den += ex;
    }
    for (int m = 1; m < 16; m <<= 1) {
        acc += __shfl_xor(acc, m, 64);
        den += __shfl_xor(den, m, 64);
    }
    if (lane == 0) {
        float r = acc / (den + 1e-16f) + ldf(bias2, 0, bf);
        if (bf) ((bf16*)out)[n] = __float2bfloat16(r);
        else    ((float*)out)[n] = r;
    }
}

// ---------------------------------------------------------------------------
extern "C" void kernel_launch(void* const* d_in, const int* in_sizes, int n_in,
                              void* d_out, int out_size, void* d_ws, size_t ws_size,
                              hipStream_t stream)
{
    const void* x        = d_in[0];
    const int*  ei       = (const int*)d_in[1];
    const void* W1       = d_in[2];
    const void* att_src1 = d_in[3];
    const void* att_dst1 = d_in[4];
    const void* b1       = d_in[5];
    const void* W2       = d_in[6];
    const void* att_src2 = d_in[7];
    const void* att_dst2 = d_in[8];
    const void* bias2    = d_in[9];

    int N = in_sizes[0] / 128;
    int E = in_sizes[1] / 2;
    int nbuck = ((N - 1) >> SB) + 1;   // 391 @ N=100k

    char* ws = (char*)d_ws;
    size_t off = 0;
    auto alloc = [&](size_t bytes) -> void* {
        void* p = ws + off;
        off = (off + bytes + 255) & ~(size_t)255;
        return p;
    };
    int*   flags   = (int*)alloc(256);
    float* a_s     = (float*)alloc((size_t)N * 4 * sizeof(float));
    float* a_d     = (float*)alloc((size_t)N * 4 * sizeof(float));
    float* h2      = (float*)alloc((size_t)N * sizeof(float));
    int*   offsets = (int*)alloc((size_t)(N + 1) * sizeof(int));
    int*   adj     = (int*)alloc((size_t)E * sizeof(int));
    uint2* ebuf    = (uint2*)alloc((size_t)E * sizeof(uint2));
    int*   bcnt    = (int*)alloc(1024 * sizeof(int));
    int*   bofs    = (int*)alloc(1028 * sizeof(int));
    int*   bcur    = (int*)alloc(1024 * sizeof(int));
    short* w1frag  = (short*)alloc(16384 * sizeof(short));
    bf16*  h1b     = (bf16*)alloc((size_t)N * 128 * sizeof(bf16));

    k_detect<<<1, 256, 0, stream>>>(ei, (const unsigned*)x, flags);
    k_zero<<<(nbuck + 255) / 256, 256, 0, stream>>>(bcnt, nbuck);
    k_w1frag<<<64, 256, 0, stream>>>(W1, flags, w1frag);

    int ebl = (E + EPB - 1) / EPB;
    k_bbin_count<<<ebl, 256, 0, stream>>>(ei, flags, bcnt, E, N, nbuck);
    k_bscan<<<1, 512, 0, stream>>>(bcnt, bofs, bcur, offsets, nbuck, E, N);
    k_bbin_scatter<<<ebl, 256, 0, stream>>>(ei, flags, bcur, ebuf, E, N, nbuck);
    k_bucket_csr<<<nbuck, 256, 0, stream>>>(ebuf, bofs, offsets, adj, N);

    k_gemm2<<<(N + 63) / 64, 256, 0, stream>>>(x, w1frag, att_src1, att_dst1,
                                               flags, h1b, a_s, a_d, N);

    k_hagg32<<<(N + 7) / 8, 256, 0, stream>>>(h1b, a_s, a_d, offsets, adj,
                                              b1, W2, flags, h2, N);

    k_agg2<<<((size_t)N * 16 + 255) / 256, 256, 0, stream>>>(
        h2, offsets, adj, att_src2, att_dst2, bias2, flags, d_out, N);
}

// Round 10
// 279.932 us; speedup vs baseline: 1.5542x; 1.0344x over previous
//
#include <hip/hip_runtime.h>
#include <hip/hip_bf16.h>
#include <math.h>

typedef __hip_bfloat16 bf16;
typedef __attribute__((ext_vector_type(8))) short short8v;
typedef __attribute__((ext_vector_type(4))) float float4v;

__device__ __forceinline__ float b2f(bf16 v) { return __bfloat162float(v); }
__device__ __forceinline__ float bs2f(unsigned short s) {
    unsigned u = ((unsigned)s) << 16;
    float f; __builtin_memcpy(&f, &u, 4); return f;
}
__device__ __forceinline__ short f2bs(float v) {
    bf16 b = __float2bfloat16(v);
    short s; __builtin_memcpy(&s, &b, 2); return s;
}
__device__ __forceinline__ float lrelu(float v) { return v > 0.f ? v : 0.2f * v; }
__device__ __forceinline__ float ldf(const void* p, size_t i, int bf) {
    return bf ? b2f(((const bf16*)p)[i]) : ((const float*)p)[i];
}
__device__ __forceinline__ int ld_src(const int* ei, int e, int E, int f64, int N) {
    int v = f64 ? (int)(((const long long*)ei)[e]) : ei[e];
    if ((unsigned)v >= (unsigned)N) v = 0;
    return v;
}
__device__ __forceinline__ int ld_dst(const int* ei, int e, int E, int f64, int N) {
    int v = f64 ? (int)(((const long long*)ei)[(size_t)E + e]) : ei[(size_t)E + e];
    if ((unsigned)v >= (unsigned)N) v = 0;
    return v;
}

#define EPB 4096   // edges per block in binning passes
#define SB  8      // bucket shift: 256 nodes per bucket

// ---------------------------------------------------------------------------
// K0: dtype detection + bcnt zeroing. flags[0]=int64 edges, flags[1]=bf16.
// ---------------------------------------------------------------------------
__global__ void k_detect(const int* __restrict__ ei, const unsigned* __restrict__ xw,
                         int* __restrict__ flags, int* __restrict__ bcnt, int nbuck)
{
    __shared__ int s_or[256];
    __shared__ int s_cnt[256];
    int t = threadIdx.x;
    for (int j = t; j < nbuck; j += 256) bcnt[j] = 0;
    int any = 0, cnt = 0;
    for (int i = t; i < 4096; i += 256) {
        any |= ei[2 * i + 1];
        unsigned e = (xw[i] >> 7) & 0xFFu;
        cnt += (e >= 100u && e <= 134u) ? 1 : 0;
    }
    s_or[t] = any; s_cnt[t] = cnt;
    __syncthreads();
    for (int s = 128; s > 0; s >>= 1) {
        if (t < s) { s_or[t] |= s_or[t + s]; s_cnt[t] += s_cnt[t + s]; }
        __syncthreads();
    }
    if (t == 0) {
        flags[0] = (s_or[0] == 0) ? 1 : 0;
        flags[1] = (s_cnt[0] > 2048) ? 1 : 0;
    }
}

// ---------------------------------------------------------------------------
// K1 combo: blocks [0,ebl) = bucket histogram; blocks [ebl,ebl+64) = W1->frag.
// w1frag[((ct*4+kk)*64 + l)*8 + j] = W1[k=kk*32+(l>>4)*8+j][n=ct*16+(l&15)]
// ---------------------------------------------------------------------------
__global__ void __launch_bounds__(256)
k_prep(const int* __restrict__ ei, const void* __restrict__ W1,
       const int* __restrict__ flags, int* __restrict__ bcnt,
       short* __restrict__ w1frag, int E, int N, int nbuck, int ebl)
{
    int t = threadIdx.x;
    if (blockIdx.x >= ebl) {   // W1 fragment repack
        int bf = flags[1];
        int idx = (blockIdx.x - ebl) * 256 + t;
        if (idx < 16384) {
            int j = idx & 7, l = (idx >> 3) & 63, kk = (idx >> 9) & 3, ct = idx >> 11;
            int k = kk * 32 + (l >> 4) * 8 + j;
            int n = ct * 16 + (l & 15);
            w1frag[idx] = bf ? ((const short*)W1)[k * 128 + n]
                             : f2bs(((const float*)W1)[k * 128 + n]);
        }
        return;
    }
    __shared__ int hist[512];
    for (int j = t; j < nbuck; j += 256) hist[j] = 0;
    __syncthreads();
    int f = flags[0];
    int beg = blockIdx.x * EPB, end = min(E, beg + EPB);
    for (int i = beg + t; i < end; i += 256)
        atomicAdd(&hist[ld_dst(ei, i, E, f, N) >> SB], 1);
    __syncthreads();
    for (int j = t; j < nbuck; j += 256)
        if (hist[j]) atomicAdd(&bcnt[j], hist[j]);
}

// ---------------------------------------------------------------------------
// K2 combo: block 0 = bucket scan (nbuck<=512 with 256 thr, pair scan);
// blocks >=1 = MFMA GEMM h1 = x @ W1 with LDS-staged x-tile + fused a_s/a_d.
// ---------------------------------------------------------------------------
#define GP 136   // LDS row pitch in shorts

__global__ void __launch_bounds__(256)
k_gemm_scan(const void* __restrict__ x, const short* __restrict__ w1frag,
            const void* __restrict__ att_src, const void* __restrict__ att_dst,
            const int* __restrict__ flags, bf16* __restrict__ h1b,
            float* __restrict__ a_s, float* __restrict__ a_d,
            const int* __restrict__ bcnt, int* __restrict__ bofs,
            int* __restrict__ bcur, int* __restrict__ offsets,
            int N, int E, int nbuck)
{
    int t = threadIdx.x;
    if (blockIdx.x == 0) {     // ---- bucket scan ----
        __shared__ int ps[256];
        int i0 = 2 * t, i1 = 2 * t + 1;
        int c0 = (i0 < nbuck) ? bcnt[i0] : 0;
        int c1 = (i1 < nbuck) ? bcnt[i1] : 0;
        int pr = c0 + c1;
        ps[t] = pr;
        __syncthreads();
        for (int s = 1; s < 256; s <<= 1) {
            int add = (t >= s) ? ps[t - s] : 0;
            __syncthreads();
            ps[t] += add;
            __syncthreads();
        }
        int excl = ps[t] - pr;
        if (i0 < nbuck) { bofs[i0] = excl; bcur[i0] = excl; }
        if (i1 < nbuck) { bofs[i1] = excl + c0; bcur[i1] = excl + c0; }
        if (t == 0) { bofs[nbuck] = E; offsets[N] = E; }
        return;
    }
    // ---- GEMM ----
    __shared__ short xs[64 * GP];   // 17,408 B; reused for C-transpose
    int bf = flags[1];
    int blk = blockIdx.x - 1;
    int base = blk * 64;
    // stage x-tile coalesced
    if (bf) {
        const short8v* xp = (const short8v*)x;   // 16 vec per row
        for (int idx = t; idx < 1024; idx += 256) {
            int m = idx >> 4, v8 = idx & 15;
            int gm = base + m;
            short8v v = (gm < N) ? xp[(size_t)gm * 16 + v8]
                                 : (short8v){0,0,0,0,0,0,0,0};
            *(short8v*)&xs[m * GP + v8 * 8] = v;
        }
    } else {
        const float4* xp = (const float4*)x;     // 32 vec per row
        for (int idx = t; idx < 2048; idx += 256) {
            int m = idx >> 5, v4 = idx & 31;
            int gm = base + m;
            float4 f = (gm < N) ? xp[(size_t)gm * 32 + v4]
                                : make_float4(0.f, 0.f, 0.f, 0.f);
            short* d = &xs[m * GP + v4 * 4];
            d[0] = f2bs(f.x); d[1] = f2bs(f.y); d[2] = f2bs(f.z); d[3] = f2bs(f.w);
        }
    }
    __syncthreads();

    int wv = t >> 6, l = t & 63, lq = l >> 4, lr = l & 15;
    int m0 = base + wv * 16;

    short8v afr[4];
#pragma unroll
    for (int kk = 0; kk < 4; ++kk)
        afr[kk] = *(const short8v*)&xs[(wv * 16 + lr) * GP + kk * 32 + lq * 8];

    float4v acc[8];
#pragma unroll
    for (int ct = 0; ct < 8; ++ct) acc[ct] = (float4v){0.f, 0.f, 0.f, 0.f};

#pragma unroll
    for (int kk = 0; kk < 4; ++kk) {
        short8v a = afr[kk];
#pragma unroll
        for (int ct = 0; ct < 8; ++ct) {
            short8v b = *(const short8v*)(w1frag + (((ct * 4 + kk) * 64 + l) << 3));
            acc[ct] = __builtin_amdgcn_mfma_f32_16x16x32_bf16(a, b, acc[ct], 0, 0, 0);
        }
    }
    __syncthreads();   // xs reuse as C buffer (wave's 16-row slab)

#pragma unroll
    for (int ct = 0; ct < 8; ++ct)
#pragma unroll
        for (int r = 0; r < 4; ++r)
            xs[(wv * 16 + lq * 4 + r) * GP + ct * 16 + lr] = f2bs(acc[ct][r]);
    __syncthreads();

    int c0 = (l & 7) * 16;
    float asv[16], adv[16];
#pragma unroll
    for (int c = 0; c < 16; ++c) {
        asv[c] = ldf(att_src, c0 + c, bf);
        adv[c] = ldf(att_dst, c0 + c, bf);
    }
#pragma unroll
    for (int p = 0; p < 2; ++p) {
        int rrow = p * 8 + (l >> 3);
        int gn = m0 + rrow;
        const short* srcp = &xs[(wv * 16 + rrow) * GP + c0];
        short8v v0 = *(const short8v*)srcp;
        short8v v1 = *(const short8v*)(srcp + 8);
        if (gn < N) {
            unsigned short* dst = (unsigned short*)h1b + (size_t)gn * 128 + c0;
            *(short8v*)dst = v0;
            *(short8v*)(dst + 8) = v1;
        }
        float ds = 0.f, dd = 0.f;
#pragma unroll
        for (int c = 0; c < 8; ++c) {
            float fv = bs2f((unsigned short)v0[c]);
            ds += fv * asv[c]; dd += fv * adv[c];
        }
#pragma unroll
        for (int c = 0; c < 8; ++c) {
            float fv = bs2f((unsigned short)v1[c]);
            ds += fv * asv[8 + c]; dd += fv * adv[8 + c];
        }
        ds += __shfl_xor(ds, 1, 64);
        dd += __shfl_xor(dd, 1, 64);
        if (gn < N && ((l & 1) == 0)) {
            int h = (l & 7) >> 1;
            a_s[(size_t)gn * 4 + h] = ds;
            a_d[(size_t)gn * 4 + h] = dd;
        }
    }
}

// ---------------------------------------------------------------------------
// K3: blocks reserve contiguous per-bucket ranges, append (src,dst).
// ---------------------------------------------------------------------------
__global__ void __launch_bounds__(256)
k_bbin_scatter(const int* __restrict__ ei, const int* __restrict__ flags,
               int* __restrict__ bcur, uint2* __restrict__ ebuf,
               int E, int N, int nbuck)
{
    __shared__ int hist[512];
    __shared__ int base[512];
    int t = threadIdx.x;
    for (int j = t; j < nbuck; j += 256) hist[j] = 0;
    __syncthreads();
    int f = flags[0];
    int beg = blockIdx.x * EPB, end = min(E, beg + EPB);
    for (int i = beg + t; i < end; i += 256)
        atomicAdd(&hist[ld_dst(ei, i, E, f, N) >> SB], 1);
    __syncthreads();
    for (int j = t; j < nbuck; j += 256) {
        base[j] = hist[j] ? atomicAdd(&bcur[j], hist[j]) : 0;
        hist[j] = 0;
    }
    __syncthreads();
    for (int i = beg + t; i < end; i += 256) {
        int d = ld_dst(ei, i, E, f, N);
        int s = ld_src(ei, i, E, f, N);
        int b = d >> SB;
        int idx = base[b] + atomicAdd(&hist[b], 1);
        ebuf[idx] = make_uint2((unsigned)s, (unsigned)d);
    }
}

// ---------------------------------------------------------------------------
// K4: one block per bucket -> node-level CSR offsets + adj.
// ---------------------------------------------------------------------------
__global__ void __launch_bounds__(256)
k_bucket_csr(const uint2* __restrict__ ebuf, const int* __restrict__ bofs,
             int* __restrict__ offsets, int* __restrict__ adj, int N)
{
    const int npb = 1 << SB;
    __shared__ int hist[npb];
    __shared__ int psum[256];
    int b = blockIdx.x, t = threadIdx.x;
    int n0 = b << SB;
    int ebeg = bofs[b], eend = bofs[b + 1];

    hist[t] = 0;
    __syncthreads();
    for (int i = ebeg + t; i < eend; i += 256)
        atomicAdd(&hist[ebuf[i].y - n0], 1);
    __syncthreads();
    int c = hist[t];
    psum[t] = c;
    __syncthreads();
    for (int st = 1; st < 256; st <<= 1) {
        int add = (t >= st) ? psum[t - st] : 0;
        __syncthreads();
        psum[t] += add;
        __syncthreads();
    }
    int run = ebeg + psum[t] - c;
    int node = n0 + t;
    hist[t] = run;
    if (node < N) offsets[node] = run;
    __syncthreads();
    for (int i = ebeg + t; i < eend; i += 256) {
        uint2 e = ebuf[i];
        int pos = atomicAdd(&hist[e.y - n0], 1);
        adj[pos] = (int)e.x;
    }
}

// ---------------------------------------------------------------------------
// K5: layer-1 softmax-aggregate, full-row barrier-free, unroll-4.
// One 32-lane group per node; lane owns head l>>3, 4 cols via ushort4.
// ---------------------------------------------------------------------------
__global__ void __launch_bounds__(256)
k_hagg32(const bf16* __restrict__ h1b, const float* __restrict__ a_s,
         const float* __restrict__ a_d, const int* __restrict__ offsets,
         const int* __restrict__ adj, const void* __restrict__ b1,
         const void* __restrict__ W2, const int* __restrict__ flags,
         float* __restrict__ h2, int N)
{
    int bf = flags[1];
    int t = threadIdx.x;
    int g = t >> 5, l = t & 31;
    int n = blockIdx.x * 8 + g;
    if (n >= N) return;
    int h = l >> 3;
    int coff = h * 32 + (l & 7) * 4;

    int beg = offsets[n], deg = offsets[n + 1] - beg;
    float adh = a_d[(size_t)n * 4 + h];
    const unsigned short* h1u = (const unsigned short*)h1b;

    float wself = __expf(lrelu(a_s[(size_t)n * 4 + h] + adh));
    ushort4 u = *(const ushort4*)(h1u + ((size_t)n << 7) + coff);
    float a0 = wself * bs2f(u.x), a1 = wself * bs2f(u.y);
    float a2 = wself * bs2f(u.z), a3 = wself * bs2f(u.w);
    float den = wself;

    int i = 0;
    for (; i + 4 <= deg; i += 4) {
        int s0 = adj[beg + i];
        int s1 = adj[beg + i + 1];
        int s2 = adj[beg + i + 2];
        int s3 = adj[beg + i + 3];
        float w0 = __expf(lrelu(a_s[(size_t)s0 * 4 + h] + adh));
        float w1 = __expf(lrelu(a_s[(size_t)s1 * 4 + h] + adh));
        float w2 = __expf(lrelu(a_s[(size_t)s2 * 4 + h] + adh));
        float w3 = __expf(lrelu(a_s[(size_t)s3 * 4 + h] + adh));
        ushort4 v0 = *(const ushort4*)(h1u + ((size_t)s0 << 7) + coff);
        ushort4 v1 = *(const ushort4*)(h1u + ((size_t)s1 << 7) + coff);
        ushort4 v2 = *(const ushort4*)(h1u + ((size_t)s2 << 7) + coff);
        ushort4 v3 = *(const ushort4*)(h1u + ((size_t)s3 << 7) + coff);
        den += (w0 + w1) + (w2 + w3);
        a0 += w0 * bs2f(v0.x) + w1 * bs2f(v1.x) + w2 * bs2f(v2.x) + w3 * bs2f(v3.x);
        a1 += w0 * bs2f(v0.y) + w1 * bs2f(v1.y) + w2 * bs2f(v2.y) + w3 * bs2f(v3.y);
        a2 += w0 * bs2f(v0.z) + w1 * bs2f(v1.z) + w2 * bs2f(v2.z) + w3 * bs2f(v3.z);
        a3 += w0 * bs2f(v0.w) + w1 * bs2f(v1.w) + w2 * bs2f(v2.w) + w3 * bs2f(v3.w);
    }
    for (; i < deg; ++i) {
        int s0 = adj[beg + i];
        float w0 = __expf(lrelu(a_s[(size_t)s0 * 4 + h] + adh));
        ushort4 v0 = *(const ushort4*)(h1u + ((size_t)s0 << 7) + coff);
        den += w0;
        a0 += w0 * bs2f(v0.x);
        a1 += w0 * bs2f(v0.y);
        a2 += w0 * bs2f(v0.z);
        a3 += w0 * bs2f(v0.w);
    }

    float inv = 1.f / (den + 1e-16f);
    float o0 = fmaxf(a0 * inv + ldf(b1, coff + 0, bf), 0.f);
    float o1 = fmaxf(a1 * inv + ldf(b1, coff + 1, bf), 0.f);
    float o2 = fmaxf(a2 * inv + ldf(b1, coff + 2, bf), 0.f);
    float o3 = fmaxf(a3 * inv + ldf(b1, coff + 3, bf), 0.f);

    float p = o0 * ldf(W2, coff + 0, bf) + o1 * ldf(W2, coff + 1, bf)
            + o2 * ldf(W2, coff + 2, bf) + o3 * ldf(W2, coff + 3, bf);
    p += __shfl_xor(p, 1, 64);
    p += __shfl_xor(p, 2, 64);
    p += __shfl_xor(p, 4, 64);
    p += __shfl_xor(p, 8, 64);
    p += __shfl_xor(p, 16, 64);
    if (l == 0) h2[n] = p;
}

// ---------------------------------------------------------------------------
// K6: layer-2 scalar softmax-aggregate, single pass. 16 lanes per node.
// ---------------------------------------------------------------------------
__global__ void k_agg2(const float* __restrict__ h2, const int* __restrict__ offsets,
                       const int* __restrict__ adj, const void* __restrict__ att_src2,
                       const void* __restrict__ att_dst2, const void* __restrict__ bias2,
                       const int* __restrict__ flags, void* __restrict__ out, int N)
{
    int bf = flags[1];
    int g = (blockIdx.x * blockDim.x + threadIdx.x) >> 4;
    int lane = threadIdx.x & 15;
    if (g >= N) return;
    int n = g;
    float as2 = ldf(att_src2, 0, bf), ad2 = ldf(att_dst2, 0, bf);
    int beg = offsets[n], end = offsets[n + 1], deg = end - beg;
    float hn = h2[n];
    float dterm = hn * ad2;

    float acc = 0.f, den = 0.f;
    if (lane == 0) {
        float ex = __expf(lrelu(hn * as2 + dterm));
        acc = ex * hn; den = ex;
    }
    for (int i = lane; i < deg; i += 16) {
        int s = adj[beg + i];
        float hs = h2[s];
        float ex = __expf(lrelu(hs * as2 + dterm));
        acc += ex * hs; den += ex;
    }
    for (int m = 1; m < 16; m <<= 1) {
        acc += __shfl_xor(acc, m, 64);
        den += __shfl_xor(den, m, 64);
    }
    if (lane == 0) {
        float r = acc / (den + 1e-16f) + ldf(bias2, 0, bf);
        if (bf) ((bf16*)out)[n] = __float2bfloat16(r);
        else    ((float*)out)[n] = r;
    }
}

// ---------------------------------------------------------------------------
extern "C" void kernel_launch(void* const* d_in, const int* in_sizes, int n_in,
                              void* d_out, int out_size, void* d_ws, size_t ws_size,
                              hipStream_t stream)
{
    const void* x        = d_in[0];
    const int*  ei       = (const int*)d_in[1];
    const void* W1       = d_in[2];
    const void* att_src1 = d_in[3];
    const void* att_dst1 = d_in[4];
    const void* b1       = d_in[5];
    const void* W2       = d_in[6];
    const void* att_src2 = d_in[7];
    const void* att_dst2 = d_in[8];
    const void* bias2    = d_in[9];

    int N = in_sizes[0] / 128;
    int E = in_sizes[1] / 2;
    int nbuck = ((N - 1) >> SB) + 1;   // 391 @ N=100k (<= 512)

    char* ws = (char*)d_ws;
    size_t off = 0;
    auto alloc = [&](size_t bytes) -> void* {
        void* p = ws + off;
        off = (off + bytes + 255) & ~(size_t)255;
        return p;
    };
    int*   flags   = (int*)alloc(256);
    float* a_s     = (float*)alloc((size_t)N * 4 * sizeof(float));
    float* a_d     = (float*)alloc((size_t)N * 4 * sizeof(float));
    float* h2      = (float*)alloc((size_t)N * sizeof(float));
    int*   offsets = (int*)alloc((size_t)(N + 1) * sizeof(int));
    int*   adj     = (int*)alloc((size_t)E * sizeof(int));
    uint2* ebuf    = (uint2*)alloc((size_t)E * sizeof(uint2));
    int*   bcnt    = (int*)alloc(1024 * sizeof(int));
    int*   bofs    = (int*)alloc(1028 * sizeof(int));
    int*   bcur    = (int*)alloc(1024 * sizeof(int));
    short* w1frag  = (short*)alloc(16384 * sizeof(short));
    bf16*  h1b     = (bf16*)alloc((size_t)N * 128 * sizeof(bf16));

    int ebl = (E + EPB - 1) / EPB;

    k_detect<<<1, 256, 0, stream>>>(ei, (const unsigned*)x, flags, bcnt, nbuck);

    k_prep<<<ebl + 64, 256, 0, stream>>>(ei, W1, flags, bcnt, w1frag,
                                         E, N, nbuck, ebl);

    k_gemm_scan<<<1 + (N + 63) / 64, 256, 0, stream>>>(
        x, w1frag, att_src1, att_dst1, flags, h1b, a_s, a_d,
        bcnt, bofs, bcur, offsets, N, E, nbuck);

    k_bbin_scatter<<<ebl, 256, 0, stream>>>(ei, flags, bcur, ebuf, E, N, nbuck);
    k_bucket_csr<<<nbuck, 256, 0, stream>>>(ebuf, bofs, offsets, adj, N);

    k_hagg32<<<(N + 7) / 8, 256, 0, stream>>>(h1b, a_s, a_d, offsets, adj,
                                              b1, W2, flags, h2, N);

    k_agg2<<<((size_t)N * 16 + 255) / 256, 256, 0, stream>>>(
        h2, offsets, adj, att_src2, att_dst2, bias2, flags, d_out, N);
}